// Round 3
// baseline (59.133 us; speedup 1.0000x reference)
//
#include <hip/hip_runtime.h>
#include <hip/hip_bf16.h>
#include <math.h>

#define Bn 2
#define Kn 8
#define Cn 256
#define HWn (128*128)
#define Sn 2048
#define BT 128   // sim block output tile (2x2 waves of 64x64)
#define SIM_BLOCKS ((Sn/BT)*(Sn/BT)*Bn)   // 512

typedef __bf16 bf16x8 __attribute__((ext_vector_type(8)));
typedef float  f32x4  __attribute__((ext_vector_type(4)));

// Wave per sample: lane loads 4 channels (c = lane + 64q) -> 4 outstanding
// misses/thread; butterfly-reduce ||f||^2 across the wave; write bf16 row.
// Block 0 also zeroes the accumulator (safe: stream-ordered before sim).
__global__ __launch_bounds__(256) void gather_kernel(
    const float* __restrict__ masks, const float* __restrict__ feats,
    const int* __restrict__ indices, ushort* __restrict__ fTb,
    float* __restrict__ mS, float* __restrict__ accum)
{
    if (blockIdx.x == 0 && threadIdx.x < 4) accum[threadIdx.x] = 0.0f;

    const int wave = threadIdx.x >> 6;
    const int lane = threadIdx.x & 63;
    const int bs = blockIdx.x * 4 + wave;
    const int b  = bs >> 11;        // / Sn
    const int s  = bs & (Sn - 1);
    const int id = indices[b * Sn + s];

    const float* fb = feats + (size_t)b * Cn * HWn + id;
    float v[4];
    #pragma unroll
    for (int q = 0; q < 4; ++q)
        v[q] = fb[(size_t)(lane + 64 * q) * HWn];

    float x = v[0]*v[0] + v[1]*v[1] + v[2]*v[2] + v[3]*v[3];
    #pragma unroll
    for (int o = 32; o > 0; o >>= 1) x += __shfl_xor(x, o);
    const float scale = 1.0f / fmaxf(sqrtf(x), 1e-12f);

    #pragma unroll
    for (int q = 0; q < 4; ++q) {
        __hip_bfloat16 hv = __float2bfloat16(v[q] * scale);
        fTb[(size_t)bs * Cn + lane + 64 * q] = *reinterpret_cast<const ushort*>(&hv);
    }

    if (lane < Kn) {
        const float lg = masks[((size_t)(b * Kn + lane)) * HWn + id];
        mS[(size_t)bs * Kn + lane] = 1.0f / (1.0f + expf(-lg));
    }
}

// MFMA Gram matrix, fragments straight from global (fTb is 2 MB, L2-resident).
// 4 waves in 2x2, each owns 64x64 (4x4 frags of 16x16x32 bf16).
// Threshold + m-diff fused; last block finalizes out = num/(den+eps).
__global__ __launch_bounds__(256, 2) void sim_kernel(
    const ushort* __restrict__ fTb, const float* __restrict__ mS,
    float* __restrict__ accum, float* __restrict__ out)
{
    const int b   = blockIdx.z;
    const int s0  = blockIdx.y * BT;
    const int t0  = blockIdx.x * BT;
    const int tid = threadIdx.x;
    const int lane = tid & 63;
    const int wave = tid >> 6;
    const int wm = wave >> 1, wn = wave & 1;
    const int l15 = lane & 15, l4 = lane >> 4;

    const ushort* F = fTb + (size_t)b * Sn * Cn;
    const ushort* pA = F + (size_t)(s0 + wm * 64 + l15) * Cn + l4 * 8;
    const ushort* pB = F + (size_t)(t0 + wn * 64 + l15) * Cn + l4 * 8;

    f32x4 acc[4][4];
    #pragma unroll
    for (int m = 0; m < 4; ++m)
        #pragma unroll
        for (int n = 0; n < 4; ++n) acc[m][n] = (f32x4){0.f, 0.f, 0.f, 0.f};

    #pragma unroll
    for (int k0 = 0; k0 < Cn; k0 += 32) {
        bf16x8 aF[4], bF[4];
        #pragma unroll
        for (int m = 0; m < 4; ++m)
            aF[m] = *reinterpret_cast<const bf16x8*>(pA + (size_t)m * 16 * Cn + k0);
        #pragma unroll
        for (int n = 0; n < 4; ++n)
            bF[n] = *reinterpret_cast<const bf16x8*>(pB + (size_t)n * 16 * Cn + k0);
        #pragma unroll
        for (int m = 0; m < 4; ++m)
            #pragma unroll
            for (int n = 0; n < 4; ++n)
                acc[m][n] = __builtin_amdgcn_mfma_f32_16x16x32_bf16(
                    aF[m], bF[n], acc[m][n], 0, 0, 0);
    }

    // C/D layout: col = lane&15, row = (lane>>4)*4 + reg  [HW-verified m89]
    float num_l = 0.0f, den_l = 0.0f;
    const float* mSb = mS + (size_t)b * Sn * Kn;
    #pragma unroll
    for (int m = 0; m < 4; ++m) {
        #pragma unroll
        for (int n = 0; n < 4; ++n) {
            #pragma unroll
            for (int r = 0; r < 4; ++r) {
                if (acc[m][n][r] > 0.95f) {
                    den_l += 1.0f;
                    const int srow = s0 + wm * 64 + m * 16 + l4 * 4 + r;
                    const int tcol = t0 + wn * 64 + n * 16 + l15;
                    const float* ma = mSb + (size_t)srow * Kn;
                    const float* mb = mSb + (size_t)tcol * Kn;
                    #pragma unroll
                    for (int k = 0; k < Kn; ++k) num_l += fabsf(ma[k] - mb[k]);
                }
            }
        }
    }

    #pragma unroll
    for (int o = 32; o > 0; o >>= 1) {
        num_l += __shfl_down(num_l, o);
        den_l += __shfl_down(den_l, o);
    }
    __shared__ float rn[4], rd[4];
    if (lane == 0) { rn[wave] = num_l; rd[wave] = den_l; }
    __syncthreads();
    if (tid == 0) {
        atomicAdd(&accum[0], rn[0] + rn[1] + rn[2] + rn[3]);
        atomicAdd(&accum[1], rd[0] + rd[1] + rd[2] + rd[3]);
        __threadfence();   // release our partials before the counter bump
        unsigned* cnt = reinterpret_cast<unsigned*>(&accum[2]);
        const unsigned done = atomicAdd(cnt, 1u);
        if (done == SIM_BLOCKS - 1) {
            // atomic reads: device-scope coherent across XCD L2s
            const float nn = atomicAdd(&accum[0], 0.0f);
            const float dd = atomicAdd(&accum[1], 0.0f);
            out[0] = nn / (dd + 1e-6f);
        }
    }
}

extern "C" void kernel_launch(void* const* d_in, const int* in_sizes, int n_in,
                              void* d_out, int out_size, void* d_ws, size_t ws_size,
                              hipStream_t stream) {
    const float* masks   = (const float*)d_in[0];   // (B,K,H,W) fp32
    const float* feats   = (const float*)d_in[1];   // (B,C,H,W) fp32
    const int*   indices = (const int*)d_in[2];     // (B,S) int32
    float* out = (float*)d_out;

    // ws: fTb (B*S*C bf16 = 2 MB) | mS (B*S*K f32 = 128 KB) | accum (4 f32)
    ushort* fTb  = (ushort*)d_ws;
    float*  mSm  = (float*)((char*)d_ws + (size_t)Bn * Sn * Cn * sizeof(ushort));
    float*  accum = mSm + (size_t)Bn * Sn * Kn;

    gather_kernel<<<Bn * Sn / 4, 256, 0, stream>>>(masks, feats, indices, fTb, mSm, accum);
    dim3 grid(Sn / BT, Sn / BT, Bn);
    sim_kernel<<<grid, 256, 0, stream>>>(fTb, mSm, accum, out);
}